// Round 15
// baseline (528.968 us; speedup 1.0000x reference)
//
#include <hip/hip_runtime.h>
#include <hip/hip_bf16.h>

#define N_NODES   20000
#define N_EDGES   100000
#define N_REL     1000
#define F_DIM     128
#define N_HEAD    4
#define HC        512      // N_HEAD * F_DIM
#define HC2       256      // HC/2 (bf16 pairs)
#define N_LAYERS  4
#define REL_EXT_ROWS 1008  // 1000 relations + 1 mean row
#define NEG_SLOPE 0.2f
#define NODE_MB   ((N_NODES + 63) / 64)      // 313
#define REL_MB    ((REL_EXT_ROWS + 63) / 64) // 16

typedef __attribute__((ext_vector_type(8))) short short8;
typedef __attribute__((ext_vector_type(4))) float floatx4;

__device__ __forceinline__ float loadIn(const void* p, size_t i, int f32) {
    if (f32) return ((const float*)p)[i];
    union { unsigned int u; float f; } c;
    c.u = ((unsigned int)((const unsigned short*)p)[i]) << 16;
    return c.f;
}

__device__ __forceinline__ unsigned short f2bf(float v) {
    __hip_bfloat16 b = __float2bfloat16(v);
    return *(unsigned short*)&b;
}

__device__ __forceinline__ void unpack2(unsigned int u, float& lo, float& hi) {
    union { unsigned int u; float f; } a, b;
    a.u = u << 16;
    b.u = u & 0xFFFF0000u;
    lo = a.f; hi = b.f;
}

// ---------------- dtype detection ----------------
__global__ void detect_kernel(const unsigned short* __restrict__ x, int* __restrict__ flag) {
    int t = threadIdx.x;  // 64
    int cnt = 0;
    for (int j = t; j < 256; j += 64) {
        int e = (x[j] >> 7) & 0xFF;
        if (e >= 143) cnt++;
    }
    for (int off = 32; off; off >>= 1) cnt += __shfl_xor(cnt, off);
    if (t == 0) flag[0] = (cnt >= 8) ? 1 : 0;
}

// ---------------- preprocessing ----------------

__global__ void hist_kernel(const int* __restrict__ dst, const int* __restrict__ rel,
                            int* __restrict__ deg, int* __restrict__ rcount) {
    int e = blockIdx.x * 256 + threadIdx.x;
    if (e < N_EDGES) {
        atomicAdd(&deg[dst[e]], 1);
        atomicAdd(&rcount[rel[e]], 1);
    }
}

__global__ void ea_mean_kernel(const int* __restrict__ rcount,
                               const void* __restrict__ relations,
                               float* __restrict__ ea_mean, const int* __restrict__ flag) {
    int f32 = flag[0];
    int b = blockIdx.x;
    int t = threadIdx.x;
    int col = t & 127;
    int rhalf = t >> 7;
    float acc = 0.f;
    for (int j = 0; j < 4; ++j) {
        int r = b * 8 + j * 2 + rhalf;
        acc += (float)rcount[r] * loadIn(relations, (size_t)r * F_DIM + col, f32);
    }
    __shared__ float part[256];
    part[t] = acc;
    __syncthreads();
    if (t < 128)
        atomicAdd(&ea_mean[col], (part[t] + part[t + 128]) * (1.f / (float)N_EDGES));
}

__global__ void relext_kernel(const void* __restrict__ relations,
                              const float* __restrict__ ea_mean,
                              unsigned short* __restrict__ rel_ext, const int* __restrict__ flag) {
    int idx = blockIdx.x * 256 + threadIdx.x;
    if (idx >= REL_EXT_ROWS * F_DIM) return;
    int f32 = flag[0];
    int r = idx >> 7;
    int c = idx & 127;
    float v;
    if (r < N_REL)       v = loadIn(relations, idx, f32);
    else if (r == N_REL) v = ea_mean[c];
    else                 v = 0.f;
    rel_ext[idx] = f2bf(v);
}

__global__ void scan_kernel(const int* __restrict__ deg,
                            int* __restrict__ row_start, int* __restrict__ cursor) {
    __shared__ int part[1024];
    int t = threadIdx.x;
    const int CH = (N_NODES + 1023) / 1024;  // 20
    int base = t * CH;
    int sum = 0;
    for (int j = 0; j < CH; ++j) {
        int idx = base + j;
        if (idx < N_NODES) sum += deg[idx];
    }
    part[t] = sum;
    __syncthreads();
    for (int off = 1; off < 1024; off <<= 1) {
        int u = (t >= off) ? part[t - off] : 0;
        __syncthreads();
        part[t] += u;
        __syncthreads();
    }
    int run = part[t] - sum;
    for (int j = 0; j < CH; ++j) {
        int idx = base + j;
        if (idx < N_NODES) {
            row_start[idx] = run;
            cursor[idx] = run;
            run += deg[idx];
        }
    }
    if (t == 1023) row_start[N_NODES] = part[1023];
}

__global__ void scatter_kernel(const int* __restrict__ src, const int* __restrict__ dst,
                               const int* __restrict__ rel, int* __restrict__ cursor,
                               int* __restrict__ csr_pack) {
    int e = blockIdx.x * 256 + threadIdx.x;
    if (e < N_EDGES) {
        int d = dst[e];
        int p = atomicAdd(&cursor[d], 1);
        csr_pack[p] = src[e] | (rel[e] << 16);
    }
}

__global__ void tail_kernel(const void* __restrict__ relations, void* __restrict__ out,
                            const int* __restrict__ flag) {
    int i = blockIdx.x * 256 + threadIdx.x;
    if (i >= N_REL * F_DIM) return;
    int f32 = flag[0];
    float v = loadIn(relations, i, f32);
    size_t o = (size_t)N_NODES * F_DIM + i;
    if (f32) ((float*)out)[o] = v;
    else     ((unsigned short*)out)[o] = f2bf(v);
}

// ---------------- weight transpose: W[l][128 k][512 n] -> Wt[mat][512 n][128 k] bf16 ----------------
__global__ void w_transpose_kernel(const void* __restrict__ Wl, const void* __restrict__ Wr,
                                   const void* __restrict__ We,
                                   unsigned short* __restrict__ Wt, const int* __restrict__ flag) {
    int f32 = flag[0];
    int k0 = blockIdx.x * 64;
    int n0 = blockIdx.y * 64;
    int mat = blockIdx.z;
    const void* src = (mat < 4) ? Wl : (mat < 8 ? Wr : We);
    size_t base = (size_t)(mat & 3) * F_DIM * HC;
    unsigned short* dst = Wt + (size_t)mat * HC * F_DIM;
    __shared__ float T[64][65];
    int t = threadIdx.x;
    int r = t >> 2, cq = t & 3;
    for (int j = 0; j < 16; ++j) {
        int n = cq * 16 + j;
        T[n][r] = loadIn(src, base + (size_t)(k0 + r) * HC + n0 + n, f32);
    }
    __syncthreads();
    for (int j = 0; j < 16; ++j) {
        int k = cq * 16 + j;
        dst[(size_t)(n0 + r) * F_DIM + k0 + k] = f2bf(T[r][k]);
    }
}

// ---------------- merged projection GEMM v2: barrier-free K-loop ----------------
// grid (NODE_MB + REL_MB, 4). Node blocks: tpb=2 tiles; rel blocks: 1 tile.
// A staged once in LDS (1 sync). B fragments load DIRECTLY from pre-transposed
// L2-resident weights (64B-contiguous per 16-lane group) -> K-loop has ZERO barriers,
// loads overlap MFMA. Epilogue via Cs LDS (2 syncs/tile) for coalesced short8 stores.
__launch_bounds__(256, 4)
__global__ void proj_kernel(const void* __restrict__ A_node, int a_input,
                            const unsigned short* __restrict__ rel_ext,
                            const unsigned short* __restrict__ Wlt,
                            const unsigned short* __restrict__ Wrt,
                            const unsigned short* __restrict__ Wet,
                            const void* __restrict__ bl, const void* __restrict__ br,
                            size_t boff,
                            unsigned short* __restrict__ xl,
                            unsigned short* __restrict__ xr,
                            unsigned short* __restrict__ re,
                            const int* __restrict__ flag) {
    __shared__ __align__(16) short As[64][136];   // 17.4 KB
    __shared__ __align__(16) short Cs[64][136];   // 17.4 KB
    int f32 = flag[0];
    int isNode = (blockIdx.x < NODE_MB);
    int m0 = (isNode ? blockIdx.x : (blockIdx.x - NODE_MB)) * 64;
    int M = isNode ? N_NODES : REL_EXT_ROWS;
    int tpb = isNode ? 2 : 1;
    int a_f32 = (isNode && a_input) ? f32 : 0;
    const void* A = isNode ? A_node : (const void*)rel_ext;
    int t = threadIdx.x;

    // stage A once: 64 rows x 128 K
    for (int j = 0; j < 4; ++j) {
        int c = t + j * 256;
        int row = c >> 4;
        int colc = (c & 15) * 8;
        int gm = m0 + row;
        short8 v = (short8){0, 0, 0, 0, 0, 0, 0, 0};
        if (gm < M) {
            size_t idx = (size_t)gm * F_DIM + colc;
            if (a_f32) {
                const float* Af = (const float*)A;
                for (int q = 0; q < 8; ++q) v[q] = (short)f2bf(Af[idx + q]);
            } else {
                v = *(const short8*)((const unsigned short*)A + idx);
            }
        }
        *(short8*)&As[row][colc] = v;
    }

    int wave = t >> 6, lane = t & 63;
    int wm = (wave >> 1) * 32, wn = (wave & 1) * 64;
    int r16 = lane & 15, quad = lane >> 4;
    __syncthreads();   // As ready

    for (int it = 0; it < tpb; ++it) {
        int nt = isNode ? (blockIdx.y * 2 + it) : blockIdx.y;
        const unsigned short* Wt = isNode ? ((nt < 4) ? Wlt : Wrt) : Wet;
        int n0 = (nt & 3) * 128;

        floatx4 acc[2][4];
        for (int mi = 0; mi < 2; ++mi)
            for (int ni = 0; ni < 4; ++ni)
                acc[mi][ni] = (floatx4){0.f, 0.f, 0.f, 0.f};

        // barrier-free K-loop: 4 steps of K=32, b from global (L2/L1-hot weights)
        #pragma unroll
        for (int ks = 0; ks < 4; ++ks) {
            short8 a[2], b[4];
            for (int mi = 0; mi < 2; ++mi)
                a[mi] = *(const short8*)&As[wm + mi * 16 + r16][ks * 32 + quad * 8];
            for (int ni = 0; ni < 4; ++ni)
                b[ni] = *(const short8*)(Wt + (size_t)(n0 + wn + ni * 16 + r16) * F_DIM
                                            + ks * 32 + quad * 8);
            for (int mi = 0; mi < 2; ++mi)
                for (int ni = 0; ni < 4; ++ni)
                    acc[mi][ni] = __builtin_amdgcn_mfma_f32_16x16x32_bf16(a[mi], b[ni], acc[mi][ni], 0, 0, 0);
        }

        const void* bias = isNode ? ((nt < 4) ? bl : br) : nullptr;
        unsigned short* out = isNode ? ((nt < 4) ? xl : xr) : re;
        __syncthreads();   // prior tile's Cs reads retired
        for (int mi = 0; mi < 2; ++mi) {
            for (int ni = 0; ni < 4; ++ni) {
                int col = wn + ni * 16 + r16;
                float bv = bias ? loadIn(bias, boff + n0 + col, f32) : 0.f;
                for (int r = 0; r < 4; ++r) {
                    int rowl = wm + mi * 16 + quad * 4 + r;
                    Cs[rowl][col] = (short)f2bf(acc[mi][ni][r] + bv);
                }
            }
        }
        __syncthreads();
        for (int j = 0; j < 4; ++j) {
            int c = t + j * 256;
            int rowl = c >> 4;
            int colc = (c & 15) * 8;
            int gm = m0 + rowl;
            if (gm < M)
                *(short8*)(out + (size_t)gm * HC + n0 + colc) =
                    *(const short8*)&Cs[rowl][colc];
        }
    }
}

// ---------------- edge kernel: one wave per node + cross-batch prefetch ----------------
// Block = 4 independent waves = 4 nodes (no LDS/barriers). Lane covers channels
// [lane*8, lane*8+8) (head = lane>>4). Batches of 4 edges with 1-batch-deep pipeline:
// batch k+1's 8 uint4 loads issue BEFORE consuming batch k. Clamped no-max exp softmax.
__launch_bounds__(256)
__global__ void edge_kernel(const uint4* __restrict__ xl4,
                            const uint4* __restrict__ xr4,
                            const uint4* __restrict__ re4,
                            const int* __restrict__ row_start,
                            const int* __restrict__ csr_pack,
                            const void* __restrict__ att, size_t att_off,
                            const void* __restrict__ bias, size_t bias_off,
                            void* __restrict__ hout, int final_layer,
                            const int* __restrict__ flag) {
    int f32 = flag[0];
    int w = threadIdx.x >> 6, lane = threadIdx.x & 63;
    int i = blockIdx.x * 4 + w;
    if (i >= N_NODES) return;

    // issue all independent head loads first
    uint4 xru = xr4[(size_t)i * 64 + lane];
    uint4 sxu = xl4[(size_t)i * 64 + lane];           // self-loop xl
    uint4 sru = re4[(size_t)N_REL * 64 + lane];       // mean rel row

    int e0 = row_start[i], e1 = row_start[i + 1];
    if (e0 < 0) e0 = 0;
    if (e1 > N_EDGES) e1 = N_EDGES;
    if (e1 < e0) e1 = e0;

    // batch-0 issue (up to 8 more loads in flight)
    uint4 xu[4], ru[4];
    int nb = e1 - e0; if (nb > 4) nb = 4;
    #pragma unroll
    for (int k = 0; k < 4; ++k) {
        if (k < nb) {
            int pk = csr_pack[e0 + k];
            int sn = pk & 0xFFFF;        if (sn >= N_NODES) sn = 0;
            int rn = (pk >> 16) & 0x3FF; if (rn > N_REL) rn = N_REL;
            xu[k] = xl4[(size_t)sn * 64 + lane];
            ru[k] = re4[(size_t)rn * 64 + lane];
        }
    }

    float xrv[8], attv[8];
    unpack2(xru.x, xrv[0], xrv[1]); unpack2(xru.y, xrv[2], xrv[3]);
    unpack2(xru.z, xrv[4], xrv[5]); unpack2(xru.w, xrv[6], xrv[7]);
    for (int q = 0; q < 8; ++q)
        attv[q] = loadIn(att, att_off + lane * 8 + q, f32);

    float s = 0.f, acc[8];
    for (int q = 0; q < 8; ++q) acc[q] = 0.f;

    auto consume = [&](uint4 xuv, uint4 ruv) {
        float xv[8], rv[8];
        unpack2(xuv.x, xv[0], xv[1]); unpack2(xuv.y, xv[2], xv[3]);
        unpack2(xuv.z, xv[4], xv[5]); unpack2(xuv.w, xv[6], xv[7]);
        unpack2(ruv.x, rv[0], rv[1]); unpack2(ruv.y, rv[2], rv[3]);
        unpack2(ruv.z, rv[4], rv[5]); unpack2(ruv.w, rv[6], rv[7]);
        float part = 0.f;
        for (int q = 0; q < 8; ++q) {
            float tt = xv[q] + xrv[q] + rv[q];
            tt = fmaxf(tt, NEG_SLOPE * tt);   // leaky_relu
            part += tt * attv[q];
        }
        for (int off = 8; off; off >>= 1) part += __shfl_xor(part, off);  // 16-lane head reduce
        part = fminf(fmaxf(part, -60.f), 60.f);
        float p = __expf(part);
        s += p;
        for (int q = 0; q < 8; ++q) acc[q] += p * xv[q];
    };

    consume(sxu, sru);   // self-loop

    int b = e0;
    while (b < e1) {
        int bn = b + 4;
        int nbn = e1 - bn; if (nbn > 4) nbn = 4; if (nbn < 0) nbn = 0;
        uint4 xun[4], run[4];
        #pragma unroll
        for (int k = 0; k < 4; ++k) {        // prefetch batch k+1 (8 independent loads)
            if (k < nbn) {
                int pk = csr_pack[bn + k];
                int sn = pk & 0xFFFF;        if (sn >= N_NODES) sn = 0;
                int rn = (pk >> 16) & 0x3FF; if (rn > N_REL) rn = N_REL;
                xun[k] = xl4[(size_t)sn * 64 + lane];
                run[k] = re4[(size_t)rn * 64 + lane];
            }
        }
        #pragma unroll
        for (int k = 0; k < 4; ++k)          // consume current batch
            if (k < nb) consume(xu[k], ru[k]);
        #pragma unroll
        for (int k = 0; k < 4; ++k) { xu[k] = xun[k]; ru[k] = run[k]; }
        b = bn; nb = nbn;
    }

    // normalize (s uniform within each 16-lane head group) + head mean
    float inv = 1.f / s;
    #pragma unroll
    for (int q = 0; q < 8; ++q) {
        float a = acc[q] * inv;
        a += __shfl_xor(a, 16);
        a += __shfl_xor(a, 32);
        acc[q] = a;
    }
    if (lane < 16) {
        if (final_layer && f32) {
            float* op = (float*)hout + (size_t)i * F_DIM + lane * 8;
            #pragma unroll
            for (int q = 0; q < 8; ++q)
                op[q] = acc[q] * 0.25f + loadIn(bias, bias_off + lane * 8 + q, f32);
        } else {
            unsigned short pkv[8];
            #pragma unroll
            for (int q = 0; q < 8; ++q)
                pkv[q] = f2bf(acc[q] * 0.25f + loadIn(bias, bias_off + lane * 8 + q, f32));
            *(short8*)((unsigned short*)hout + (size_t)i * F_DIM + lane * 8) = *(short8*)pkv;
        }
    }
}

// ---------------- launch ----------------

extern "C" void kernel_launch(void* const* d_in, const int* in_sizes, int n_in,
                              void* d_out, int out_size, void* d_ws, size_t ws_size,
                              hipStream_t stream) {
    const void* x          = d_in[0];
    const int*  edge_index = (const int*)d_in[1];
    const void* relations  = d_in[2];
    const int*  rel_index  = (const int*)d_in[3];
    const void* Wl         = d_in[4];
    const void* bl         = d_in[5];
    const void* Wr         = d_in[6];
    const void* br         = d_in[7];
    const void* We         = d_in[8];
    const void* att        = d_in[9];
    const void* bias       = d_in[10];

    char* ws = (char*)d_ws;
    size_t off = 0;
    auto alloc = [&](size_t bytes) -> void* {
        void* p = ws + off;
        off = (off + bytes + 255) & ~(size_t)255;
        return p;
    };
    int*            flag     = (int*)alloc(4);
    int*            deg      = (int*)alloc(N_NODES * 4);
    int*            row_start= (int*)alloc((N_NODES + 1) * 4);
    int*            cursor   = (int*)alloc(N_NODES * 4);
    int*            rcount   = (int*)alloc(N_REL * 4);
    float*          ea_mean  = (float*)alloc(F_DIM * 4);
    int*            csr_pack = (int*)alloc(N_EDGES * 4);
    unsigned short* rel_ext  = (unsigned short*)alloc((size_t)REL_EXT_ROWS * F_DIM * 2);
    unsigned short* Wt       = (unsigned short*)alloc((size_t)12 * HC * F_DIM * 2);  // 1.57 MB
    unsigned short* re       = (unsigned short*)alloc((size_t)REL_EXT_ROWS * HC * 2);
    unsigned short* hbuf     = (unsigned short*)alloc((size_t)N_NODES * F_DIM * 2);
    unsigned short* xl       = (unsigned short*)alloc((size_t)N_NODES * HC * 2);
    unsigned short* xr       = (unsigned short*)alloc((size_t)N_NODES * HC * 2);
    // total ~49 MB

    const int* esrc = edge_index;
    const int* edst = edge_index + N_EDGES;

    detect_kernel<<<1, 64, 0, stream>>>((const unsigned short*)x, flag);
    hipMemsetAsync(rcount, 0, N_REL * 4, stream);
    hipMemsetAsync(deg, 0, N_NODES * 4, stream);
    hipMemsetAsync(ea_mean, 0, F_DIM * 4, stream);
    hist_kernel<<<(N_EDGES + 255) / 256, 256, 0, stream>>>(edst, rel_index, deg, rcount);
    ea_mean_kernel<<<N_REL / 8, 256, 0, stream>>>(rcount, relations, ea_mean, flag);
    relext_kernel<<<(REL_EXT_ROWS * F_DIM + 255) / 256, 256, 0, stream>>>(relations, ea_mean, rel_ext, flag);
    scan_kernel<<<1, 1024, 0, stream>>>(deg, row_start, cursor);
    scatter_kernel<<<(N_EDGES + 255) / 256, 256, 0, stream>>>(esrc, edst, rel_index, cursor, csr_pack);
    w_transpose_kernel<<<dim3(2, 8, 12), 256, 0, stream>>>(Wl, Wr, We, Wt, flag);
    tail_kernel<<<(N_REL * F_DIM + 255) / 256, 256, 0, stream>>>(relations, d_out, flag);

    const void* hin = x;
    int a_input = 1;
    for (int l = 0; l < N_LAYERS; ++l) {
        const unsigned short* Wlt = Wt + (size_t)l * HC * F_DIM;
        const unsigned short* Wrt = Wt + (size_t)(4 + l) * HC * F_DIM;
        const unsigned short* Wet = Wt + (size_t)(8 + l) * HC * F_DIM;
        // merged node+rel projection: 329 x 4 blocks
        proj_kernel<<<dim3(NODE_MB + REL_MB, 4), 256, 0, stream>>>(
            hin, a_input, rel_ext, Wlt, Wrt, Wet,
            bl, br, (size_t)l * HC,
            xl, xr, re, flag);
        int final_layer = (l == N_LAYERS - 1);
        void* hout = final_layer ? d_out : (void*)hbuf;
        edge_kernel<<<(N_NODES + 3) / 4, 256, 0, stream>>>(
            (const uint4*)xl, (const uint4*)xr, (const uint4*)re,
            row_start, csr_pack,
            att, (size_t)l * N_HEAD * F_DIM,
            bias, (size_t)l * F_DIM,
            hout, final_layer, flag);
        hin = hbuf;
        a_input = 0;
    }
}

// Round 16
// 429.970 us; speedup vs baseline: 1.2302x; 1.2302x over previous
//
#include <hip/hip_runtime.h>
#include <hip/hip_bf16.h>

#define N_NODES   20000
#define N_EDGES   100000
#define N_REL     1000
#define F_DIM     128
#define N_HEAD    4
#define HC        512      // N_HEAD * F_DIM
#define HC2       256      // HC/2 (bf16 pairs)
#define N_LAYERS  4
#define REL_EXT_ROWS 1008  // 1000 relations + 1 mean row
#define NEG_SLOPE 0.2f
#define NODE_MB   ((N_NODES + 63) / 64)      // 313
#define REL_MB    ((REL_EXT_ROWS + 63) / 64) // 16

typedef __attribute__((ext_vector_type(8))) short short8;
typedef __attribute__((ext_vector_type(4))) float floatx4;

__device__ __forceinline__ float loadIn(const void* p, size_t i, int f32) {
    if (f32) return ((const float*)p)[i];
    union { unsigned int u; float f; } c;
    c.u = ((unsigned int)((const unsigned short*)p)[i]) << 16;
    return c.f;
}

__device__ __forceinline__ unsigned short f2bf(float v) {
    __hip_bfloat16 b = __float2bfloat16(v);
    return *(unsigned short*)&b;
}

__device__ __forceinline__ void unpack2(unsigned int u, float& lo, float& hi) {
    union { unsigned int u; float f; } a, b;
    a.u = u << 16;
    b.u = u & 0xFFFF0000u;
    lo = a.f; hi = b.f;
}

// ---------------- dtype detection ----------------
__global__ void detect_kernel(const unsigned short* __restrict__ x, int* __restrict__ flag) {
    int t = threadIdx.x;  // 64
    int cnt = 0;
    for (int j = t; j < 256; j += 64) {
        int e = (x[j] >> 7) & 0xFF;
        if (e >= 143) cnt++;
    }
    for (int off = 32; off; off >>= 1) cnt += __shfl_xor(cnt, off);
    if (t == 0) flag[0] = (cnt >= 8) ? 1 : 0;
}

// ---------------- preprocessing ----------------

__global__ void hist_kernel(const int* __restrict__ dst, const int* __restrict__ rel,
                            int* __restrict__ deg, int* __restrict__ rcount) {
    int e = blockIdx.x * 256 + threadIdx.x;
    if (e < N_EDGES) {
        atomicAdd(&deg[dst[e]], 1);
        atomicAdd(&rcount[rel[e]], 1);
    }
}

__global__ void ea_mean_kernel(const int* __restrict__ rcount,
                               const void* __restrict__ relations,
                               float* __restrict__ ea_mean, const int* __restrict__ flag) {
    int f32 = flag[0];
    int b = blockIdx.x;
    int t = threadIdx.x;
    int col = t & 127;
    int rhalf = t >> 7;
    float acc = 0.f;
    for (int j = 0; j < 4; ++j) {
        int r = b * 8 + j * 2 + rhalf;
        acc += (float)rcount[r] * loadIn(relations, (size_t)r * F_DIM + col, f32);
    }
    __shared__ float part[256];
    part[t] = acc;
    __syncthreads();
    if (t < 128)
        atomicAdd(&ea_mean[col], (part[t] + part[t + 128]) * (1.f / (float)N_EDGES));
}

__global__ void relext_kernel(const void* __restrict__ relations,
                              const float* __restrict__ ea_mean,
                              unsigned short* __restrict__ rel_ext, const int* __restrict__ flag) {
    int idx = blockIdx.x * 256 + threadIdx.x;
    if (idx >= REL_EXT_ROWS * F_DIM) return;
    int f32 = flag[0];
    int r = idx >> 7;
    int c = idx & 127;
    float v;
    if (r < N_REL)       v = loadIn(relations, idx, f32);
    else if (r == N_REL) v = ea_mean[c];
    else                 v = 0.f;
    rel_ext[idx] = f2bf(v);
}

__global__ void scan_kernel(const int* __restrict__ deg,
                            int* __restrict__ row_start, int* __restrict__ cursor) {
    __shared__ int part[1024];
    int t = threadIdx.x;
    const int CH = (N_NODES + 1023) / 1024;  // 20
    int base = t * CH;
    int sum = 0;
    for (int j = 0; j < CH; ++j) {
        int idx = base + j;
        if (idx < N_NODES) sum += deg[idx];
    }
    part[t] = sum;
    __syncthreads();
    for (int off = 1; off < 1024; off <<= 1) {
        int u = (t >= off) ? part[t - off] : 0;
        __syncthreads();
        part[t] += u;
        __syncthreads();
    }
    int run = part[t] - sum;
    for (int j = 0; j < CH; ++j) {
        int idx = base + j;
        if (idx < N_NODES) {
            row_start[idx] = run;
            cursor[idx] = run;
            run += deg[idx];
        }
    }
    if (t == 1023) row_start[N_NODES] = part[1023];
}

__global__ void scatter_kernel(const int* __restrict__ src, const int* __restrict__ dst,
                               const int* __restrict__ rel, int* __restrict__ cursor,
                               int* __restrict__ csr_pack) {
    int e = blockIdx.x * 256 + threadIdx.x;
    if (e < N_EDGES) {
        int d = dst[e];
        int p = atomicAdd(&cursor[d], 1);
        csr_pack[p] = src[e] | (rel[e] << 16);
    }
}

__global__ void tail_kernel(const void* __restrict__ relations, void* __restrict__ out,
                            const int* __restrict__ flag) {
    int i = blockIdx.x * 256 + threadIdx.x;
    if (i >= N_REL * F_DIM) return;
    int f32 = flag[0];
    float v = loadIn(relations, i, f32);
    size_t o = (size_t)N_NODES * F_DIM + i;
    if (f32) ((float*)out)[o] = v;
    else     ((unsigned short*)out)[o] = f2bf(v);
}

// ---------------- weight transpose: W[l][128 k][512 n] -> Wt[mat][512 n][128 k] bf16 ----------------
__global__ void w_transpose_kernel(const void* __restrict__ Wl, const void* __restrict__ Wr,
                                   const void* __restrict__ We,
                                   unsigned short* __restrict__ Wt, const int* __restrict__ flag) {
    int f32 = flag[0];
    int k0 = blockIdx.x * 64;
    int n0 = blockIdx.y * 64;
    int mat = blockIdx.z;
    const void* src = (mat < 4) ? Wl : (mat < 8 ? Wr : We);
    size_t base = (size_t)(mat & 3) * F_DIM * HC;
    unsigned short* dst = Wt + (size_t)mat * HC * F_DIM;
    __shared__ float T[64][65];
    int t = threadIdx.x;
    int r = t >> 2, cq = t & 3;
    for (int j = 0; j < 16; ++j) {
        int n = cq * 16 + j;
        T[n][r] = loadIn(src, base + (size_t)(k0 + r) * HC + n0 + n, f32);
    }
    __syncthreads();
    for (int j = 0; j < 16; ++j) {
        int k = cq * 16 + j;
        dst[(size_t)(n0 + r) * F_DIM + k0 + k] = f2bf(T[r][k]);
    }
}

// ---------------- merged projection GEMM (node + rel in one launch) ----------------
// grid (NODE_MB + REL_MB, 4). Node blocks: tpb=2 tiles (y*2+it; nt<4 -> Wl/bl/xl else
// Wr/br/xr). Rel blocks: 1 tile (nt=y), We -> re, no bias. A staged once; Bt staged
// per k-half via LDS (measured best vs direct-global B in r15).
__launch_bounds__(256, 4)
__global__ void proj_kernel(const void* __restrict__ A_node, int a_input,
                            const unsigned short* __restrict__ rel_ext,
                            const unsigned short* __restrict__ Wlt,
                            const unsigned short* __restrict__ Wrt,
                            const unsigned short* __restrict__ Wet,
                            const void* __restrict__ bl, const void* __restrict__ br,
                            size_t boff,
                            unsigned short* __restrict__ xl,
                            unsigned short* __restrict__ xr,
                            unsigned short* __restrict__ re,
                            const int* __restrict__ flag) {
    __shared__ __align__(16) short As[64][136];    // 17.4 KB
    __shared__ __align__(16) short BtRaw[128 * 72];// 18.4 KB; Cs view: stride 136
    int f32 = flag[0];
    int isNode = (blockIdx.x < NODE_MB);
    int m0 = (isNode ? blockIdx.x : (blockIdx.x - NODE_MB)) * 64;
    int M = isNode ? N_NODES : REL_EXT_ROWS;
    int tpb = isNode ? 2 : 1;
    int a_f32 = (isNode && a_input) ? f32 : 0;
    const void* A = isNode ? A_node : (const void*)rel_ext;
    int t = threadIdx.x;

    for (int j = 0; j < 4; ++j) {
        int c = t + j * 256;
        int row = c >> 4;
        int colc = (c & 15) * 8;
        int gm = m0 + row;
        short8 v = (short8){0, 0, 0, 0, 0, 0, 0, 0};
        if (gm < M) {
            size_t idx = (size_t)gm * F_DIM + colc;
            if (a_f32) {
                const float* Af = (const float*)A;
                for (int q = 0; q < 8; ++q) v[q] = (short)f2bf(Af[idx + q]);
            } else {
                v = *(const short8*)((const unsigned short*)A + idx);
            }
        }
        *(short8*)&As[row][colc] = v;
    }

    int wave = t >> 6, lane = t & 63;
    int wm = (wave >> 1) * 32, wn = (wave & 1) * 64;
    int r16 = lane & 15, quad = lane >> 4;

    for (int it = 0; it < tpb; ++it) {
        int nt = isNode ? (blockIdx.y * 2 + it) : blockIdx.y;
        const unsigned short* Wt = isNode ? ((nt < 4) ? Wlt : Wrt) : Wet;
        int n0 = (nt & 3) * 128;

        floatx4 acc[2][4];
        for (int mi = 0; mi < 2; ++mi)
            for (int ni = 0; ni < 4; ++ni)
                acc[mi][ni] = (floatx4){0.f, 0.f, 0.f, 0.f};

        for (int half = 0; half < 2; ++half) {
            __syncthreads();
            for (int j = 0; j < 4; ++j) {
                int c = t + j * 256;
                int nl = c >> 3;
                int kc = (c & 7) * 8;
                *(short8*)&BtRaw[nl * 72 + kc] =
                    *(const short8*)(Wt + (size_t)(n0 + nl) * F_DIM + half * 64 + kc);
            }
            __syncthreads();

            for (int kk = 0; kk < 2; ++kk) {
                short8 a[2], b[4];
                for (int mi = 0; mi < 2; ++mi)
                    a[mi] = *(const short8*)&As[wm + mi * 16 + r16][half * 64 + kk * 32 + quad * 8];
                for (int ni = 0; ni < 4; ++ni)
                    b[ni] = *(const short8*)&BtRaw[(wn + ni * 16 + r16) * 72 + kk * 32 + quad * 8];
                for (int mi = 0; mi < 2; ++mi)
                    for (int ni = 0; ni < 4; ++ni)
                        acc[mi][ni] = __builtin_amdgcn_mfma_f32_16x16x32_bf16(a[mi], b[ni], acc[mi][ni], 0, 0, 0);
            }
        }

        const void* bias = isNode ? ((nt < 4) ? bl : br) : nullptr;
        unsigned short* out = isNode ? ((nt < 4) ? xl : xr) : re;
        __syncthreads();
        for (int mi = 0; mi < 2; ++mi) {
            for (int ni = 0; ni < 4; ++ni) {
                int col = wn + ni * 16 + r16;
                float bv = bias ? loadIn(bias, boff + n0 + col, f32) : 0.f;
                for (int r = 0; r < 4; ++r) {
                    int rowl = wm + mi * 16 + quad * 4 + r;
                    BtRaw[rowl * 136 + col] = (short)f2bf(acc[mi][ni][r] + bv);
                }
            }
        }
        __syncthreads();
        for (int j = 0; j < 4; ++j) {
            int c = t + j * 256;
            int rowl = c >> 4;
            int colc = (c & 15) * 8;
            int gm = m0 + rowl;
            if (gm < M)
                *(short8*)(out + (size_t)gm * HC + n0 + colc) =
                    *(const short8*)&BtRaw[rowl * 136 + colc];
        }
    }
}

// ---------------- edge kernel: r13 (best measured, 51.9 us) ----------------
// One block per dst node; wave h = head h; ALL waves walk ALL edges; lane owns channels
// (2*lane, 2*lane+1). Batches of 4 edges, 1-batch-deep load-then-compute pipeline
// (8 independent loads in flight). Clamped no-max exp softmax.
__launch_bounds__(256)
__global__ void edge_kernel(const unsigned int* __restrict__ xl2,
                            const unsigned int* __restrict__ xr2,
                            const unsigned int* __restrict__ re2,
                            const int* __restrict__ row_start,
                            const int* __restrict__ csr_pack,
                            const void* __restrict__ att, size_t att_off,
                            const void* __restrict__ bias, size_t bias_off,
                            void* __restrict__ hout, int final_layer,
                            const int* __restrict__ flag) {
    int f32 = flag[0];
    int i = blockIdx.x;
    int h = threadIdx.x >> 6;
    int lane = threadIdx.x & 63;
    int pidx = h * 64 + lane;

    float xr0, xr1; unpack2(xr2[(size_t)i * HC2 + pidx], xr0, xr1);
    float a0 = loadIn(att, att_off + h * F_DIM + 2 * lane, f32);
    float a1 = loadIn(att, att_off + h * F_DIM + 2 * lane + 1, f32);
    float er0, er1; unpack2(re2[(size_t)N_REL * HC2 + pidx], er0, er1);

    // self-loop seed
    float xs0, xs1; unpack2(xl2[(size_t)i * HC2 + pidx], xs0, xs1);
    float t0 = xs0 + xr0 + er0;
    float t1 = xs1 + xr1 + er1;
    t0 = fmaxf(t0, NEG_SLOPE * t0);
    t1 = fmaxf(t1, NEG_SLOPE * t1);
    float part = t0 * a0 + t1 * a1;
    for (int off = 32; off; off >>= 1) part += __shfl_xor(part, off);
    part = fminf(fmaxf(part, -60.f), 60.f);
    float p = __expf(part);
    float s = p, acc0 = p * xs0, acc1 = p * xs1;

    int e0 = row_start[i], e1 = row_start[i + 1];
    if (e0 < 0) e0 = 0;
    if (e1 > N_EDGES) e1 = N_EDGES;
    if (e1 < e0) e1 = e0;

    unsigned int xv[4], rv[4];
    #pragma unroll
    for (int k = 0; k < 4; ++k) { xv[k] = 0; rv[k] = 0; }
    int b = e0;
    int nb = e1 - b; if (nb > 4) nb = 4;
    #pragma unroll
    for (int k = 0; k < 4; ++k) {
        if (k < nb) {
            int pk = csr_pack[b + k];
            int sn = pk & 0xFFFF;        if (sn >= N_NODES) sn = 0;
            int rn = (pk >> 16) & 0x3FF; if (rn > N_REL) rn = N_REL;
            xv[k] = xl2[(size_t)sn * HC2 + pidx];
            rv[k] = re2[(size_t)rn * HC2 + pidx];
        }
    }
    while (b < e1) {
        int bn = b + 4;
        int nbn = e1 - bn; if (nbn > 4) nbn = 4; if (nbn < 0) nbn = 0;
        unsigned int xvn[4], rvn[4];
        #pragma unroll
        for (int k = 0; k < 4; ++k) { xvn[k] = 0; rvn[k] = 0; }
        #pragma unroll
        for (int k = 0; k < 4; ++k) {       // prefetch next batch: 8 independent loads
            if (k < nbn) {
                int pk = csr_pack[bn + k];
                int sn = pk & 0xFFFF;        if (sn >= N_NODES) sn = 0;
                int rn = (pk >> 16) & 0x3FF; if (rn > N_REL) rn = N_REL;
                xvn[k] = xl2[(size_t)sn * HC2 + pidx];
                rvn[k] = re2[(size_t)rn * HC2 + pidx];
            }
        }
        #pragma unroll
        for (int k = 0; k < 4; ++k) {       // compute current batch (independent reduces)
            if (k < nb) {
                float xl0, xl1; unpack2(xv[k], xl0, xl1);
                float ee0, ee1; unpack2(rv[k], ee0, ee1);
                float u0 = xl0 + xr0 + ee0;
                float u1 = xl1 + xr1 + ee1;
                u0 = fmaxf(u0, NEG_SLOPE * u0);
                u1 = fmaxf(u1, NEG_SLOPE * u1);
                float pe = u0 * a0 + u1 * a1;
                for (int off = 32; off; off >>= 1) pe += __shfl_xor(pe, off);
                pe = fminf(fmaxf(pe, -60.f), 60.f);
                float pp = __expf(pe);
                s += pp;
                acc0 += pp * xl0;
                acc1 += pp * xl1;
            }
        }
        #pragma unroll
        for (int k = 0; k < 4; ++k) { xv[k] = xvn[k]; rv[k] = rvn[k]; }
        b = bn; nb = nbn;
    }

    float inv = 1.f / s;
    __shared__ float lsum[N_HEAD][F_DIM];
    lsum[h][2 * lane]     = acc0 * inv;
    lsum[h][2 * lane + 1] = acc1 * inv;
    __syncthreads();
    if (threadIdx.x < F_DIM) {
        int c = threadIdx.x;
        float v = (lsum[0][c] + lsum[1][c] + lsum[2][c] + lsum[3][c]) * 0.25f
                + loadIn(bias, bias_off + c, f32);
        size_t o = (size_t)i * F_DIM + c;
        if (final_layer && f32) ((float*)hout)[o] = v;
        else                    ((unsigned short*)hout)[o] = f2bf(v);
    }
}

// ---------------- launch ----------------

extern "C" void kernel_launch(void* const* d_in, const int* in_sizes, int n_in,
                              void* d_out, int out_size, void* d_ws, size_t ws_size,
                              hipStream_t stream) {
    const void* x          = d_in[0];
    const int*  edge_index = (const int*)d_in[1];
    const void* relations  = d_in[2];
    const int*  rel_index  = (const int*)d_in[3];
    const void* Wl         = d_in[4];
    const void* bl         = d_in[5];
    const void* Wr         = d_in[6];
    const void* br         = d_in[7];
    const void* We         = d_in[8];
    const void* att        = d_in[9];
    const void* bias       = d_in[10];

    char* ws = (char*)d_ws;
    size_t off = 0;
    auto alloc = [&](size_t bytes) -> void* {
        void* p = ws + off;
        off = (off + bytes + 255) & ~(size_t)255;
        return p;
    };
    int*            flag     = (int*)alloc(4);
    // deg / rcount / ea_mean contiguous -> single memset covers all three
    char*           zero0    = ws + off;
    int*            deg      = (int*)alloc(N_NODES * 4);
    int*            rcount   = (int*)alloc(N_REL * 4);
    float*          ea_mean  = (float*)alloc(F_DIM * 4);
    size_t          zlen     = (size_t)((ws + off) - zero0);
    int*            row_start= (int*)alloc((N_NODES + 1) * 4);
    int*            cursor   = (int*)alloc(N_NODES * 4);
    int*            csr_pack = (int*)alloc(N_EDGES * 4);
    unsigned short* rel_ext  = (unsigned short*)alloc((size_t)REL_EXT_ROWS * F_DIM * 2);
    unsigned short* Wt       = (unsigned short*)alloc((size_t)12 * HC * F_DIM * 2);  // 1.57 MB
    unsigned short* re       = (unsigned short*)alloc((size_t)REL_EXT_ROWS * HC * 2);
    unsigned short* hbuf     = (unsigned short*)alloc((size_t)N_NODES * F_DIM * 2);
    unsigned short* xl       = (unsigned short*)alloc((size_t)N_NODES * HC * 2);
    unsigned short* xr       = (unsigned short*)alloc((size_t)N_NODES * HC * 2);
    // total ~49 MB

    const int* esrc = edge_index;
    const int* edst = edge_index + N_EDGES;

    detect_kernel<<<1, 64, 0, stream>>>((const unsigned short*)x, flag);
    hipMemsetAsync(zero0, 0, zlen, stream);
    hist_kernel<<<(N_EDGES + 255) / 256, 256, 0, stream>>>(edst, rel_index, deg, rcount);
    ea_mean_kernel<<<N_REL / 8, 256, 0, stream>>>(rcount, relations, ea_mean, flag);
    relext_kernel<<<(REL_EXT_ROWS * F_DIM + 255) / 256, 256, 0, stream>>>(relations, ea_mean, rel_ext, flag);
    scan_kernel<<<1, 1024, 0, stream>>>(deg, row_start, cursor);
    scatter_kernel<<<(N_EDGES + 255) / 256, 256, 0, stream>>>(esrc, edst, rel_index, cursor, csr_pack);
    w_transpose_kernel<<<dim3(2, 8, 12), 256, 0, stream>>>(Wl, Wr, We, Wt, flag);
    tail_kernel<<<(N_REL * F_DIM + 255) / 256, 256, 0, stream>>>(relations, d_out, flag);

    const void* hin = x;
    int a_input = 1;
    for (int l = 0; l < N_LAYERS; ++l) {
        const unsigned short* Wlt = Wt + (size_t)l * HC * F_DIM;
        const unsigned short* Wrt = Wt + (size_t)(4 + l) * HC * F_DIM;
        const unsigned short* Wet = Wt + (size_t)(8 + l) * HC * F_DIM;
        // merged node+rel projection: 329 x 4 blocks
        proj_kernel<<<dim3(NODE_MB + REL_MB, 4), 256, 0, stream>>>(
            hin, a_input, rel_ext, Wlt, Wrt, Wet,
            bl, br, (size_t)l * HC,
            xl, xr, re, flag);
        int final_layer = (l == N_LAYERS - 1);
        void* hout = final_layer ? d_out : (void*)hbuf;
        edge_kernel<<<N_NODES, 256, 0, stream>>>(
            (const unsigned int*)xl, (const unsigned int*)xr, (const unsigned int*)re,
            row_start, csr_pack,
            att, (size_t)l * N_HEAD * F_DIM,
            bias, (size_t)l * F_DIM,
            hout, final_layer, flag);
        hin = hbuf;
        a_input = 0;
    }
}